// Round 7
// baseline (375.704 us; speedup 1.0000x reference)
//
#include <hip/hip_runtime.h>
#include <math.h>

typedef _Float16 f16;
typedef f16 f16x8 __attribute__((ext_vector_type(8)));
typedef float f32x4 __attribute__((ext_vector_type(4)));

#define N_ROWS 32768
#define DIM    256
#define KCODES 4096

// ws layout (float units)
#define WS_ET    0                           // et [4096][256] f32        (4 MB)
#define WS_BN    (WS_ET + KCODES*DIM)        // code norms [4096]
#define WS_AN    (WS_BN + KCODES)            // row norms [32768]
#define WS_PART  (WS_AN + N_ROWS)            // loss partials [8192]
#define WS_BEST  (WS_PART + 8192)            // u64 bests [32768] = 65536 floats
#define WS_BP    (WS_BEST + 65536)           // B' images  4 MB = 1048576 floats
#define WS_AP    (WS_BP + 1048576)           // A' images 32 MB = 8388608 floats

// Image geometry (R7): half-chunk = [128 rows][32 f16 = 64 B], swizzled:
//   byte_in_row = ((d%32)*2) ^ ((row & 3) << 4)     (16-B slot granularity)
// Per-128-row A' block (131072 B): H plane = 8 hc x 8192 @0, L plane @65536.
// Per-128-code B' block (131072 B): EH @0, EL @65536.
// sim*2^20 = H.EH + L.EH + H.EL (l*l dropped, ~4e-7 in dist units)
// hc = (c,ks) in R6's order -> accumulation order identical to R6.

// ---------------------------------------------------------------- helpers
__device__ __forceinline__ void gload16(const void* g, void* l) {
#if __has_builtin(__builtin_amdgcn_global_load_lds)
    __builtin_amdgcn_global_load_lds(
        (const __attribute__((address_space(1))) unsigned int*)g,
        (__attribute__((address_space(3))) unsigned int*)l, 16, 0, 0);
#else
    *(float4*)l = *(const float4*)g;
#endif
}

// ---------------------------------------------------------------- row norms (codes)
__global__ void vq_rownorm(const float* __restrict__ src, float* __restrict__ out, int nrows) {
    int w    = threadIdx.x >> 6;
    int lane = threadIdx.x & 63;
    int row  = blockIdx.x * 4 + w;
    if (row >= nrows) return;
    float4 v = *(const float4*)&src[row * DIM + lane * 4];
    float  s = v.x * v.x + v.y * v.y + v.z * v.z + v.w * v.w;
#pragma unroll
    for (int m = 1; m < 64; m <<= 1) s += __shfl_xor(s, m);
    if (lane == 0) out[row] = s;
}

// ---------------------------------------------------------------- A' prep (+ fused x row norms)
// lane covers d = lane*4 .. lane*4+3 of row m; hc = lane>>3.
__global__ void vq_prep_a(const float* __restrict__ x, char* __restrict__ Ap,
                          float* __restrict__ An) {
    const int t = threadIdx.x;
    const int lane = t & 63, w = t >> 6;
    const size_t row0 = (size_t)blockIdx.x * 128;
    char* base = Ap + (size_t)blockIdx.x * 131072;
    const int hc  = lane >> 3;               // d/32
    const int db  = (lane & 7) * 8;          // (d%32)*2 : byte of 4-f16 group
#pragma unroll 4
    for (int it = 0; it < 32; ++it) {
        const int m = it * 4 + w;
        float4 v = *(const float4*)&x[(row0 + m) * DIM + lane * 4];
        float vs[4] = { v.x, v.y, v.z, v.w };
        uint32_t hw[2], lw[2];
#pragma unroll
        for (int p = 0; p < 2; ++p) {
            uint32_t hword = 0, lword = 0;
#pragma unroll
            for (int j = 0; j < 2; ++j) {
                float s = vs[p * 2 + j] * 1024.0f;
                f16 h = (f16)s;
                f16 l = (f16)(s - (float)h);
                hword |= (uint32_t)__builtin_bit_cast(uint16_t, h) << (16 * j);
                lword |= (uint32_t)__builtin_bit_cast(uint16_t, l) << (16 * j);
            }
            hw[p] = hword; lw[p] = lword;
        }
        const int off = hc * 8192 + m * 64 + (db ^ ((m & 3) << 4));
        *(uint2*)(base + off)         = *(uint2*)hw;
        *(uint2*)(base + 65536 + off) = *(uint2*)lw;
        float s = v.x * v.x + v.y * v.y + v.z * v.z + v.w * v.w;
#pragma unroll
        for (int mm = 1; mm < 64; mm <<= 1) s += __shfl_xor(s, mm);
        if (lane == 0) An[row0 + m] = s;
    }
}

// ---------------------------------------------------------------- B' prep (+ writes et)
__global__ void vq_prep_b(const float* __restrict__ e, char* __restrict__ Bp,
                          float* __restrict__ et) {
    __shared__ float lt[128][65];   // [n_loc][dd]
    const int t  = threadIdx.x;
    const int jb = blockIdx.x >> 2;
    const int c  = blockIdx.x & 3;
    const int d0 = c * 64, n0 = jb * 128;
#pragma unroll
    for (int it = 0; it < 8; ++it) {
        int linear = it * 256 + t;
        int drow = linear >> 5;
        int ncol = (linear & 31) * 4;
        float4 v = *(const float4*)&e[(size_t)(d0 + drow) * KCODES + n0 + ncol];
        lt[ncol + 0][drow] = v.x;
        lt[ncol + 1][drow] = v.y;
        lt[ncol + 2][drow] = v.z;
        lt[ncol + 3][drow] = v.w;
    }
    __syncthreads();
    // transposed slab -> et
#pragma unroll
    for (int it = 0; it < 8; ++it) {
        int lin = it * 256 + t;
        int n = lin >> 4, q = lin & 15;
        float4 v = { lt[n][q*4], lt[n][q*4+1], lt[n][q*4+2], lt[n][q*4+3] };
        *(float4*)&et[(size_t)(n0 + n) * DIM + d0 + q * 4] = v;
    }
    char* pbase = Bp + (size_t)jb * 131072;
    const int n_loc = t >> 1;
    const int shalf = t & 1;
#pragma unroll
    for (int g = 0; g < 4; ++g) {
        const int dd8 = shalf * 32 + g * 8;            // local d of 8-group
        uint32_t ehw[4], elw[4];
#pragma unroll
        for (int p = 0; p < 4; ++p) {
            uint32_t hword = 0, lword = 0;
#pragma unroll
            for (int j = 0; j < 2; ++j) {
                float s = lt[n_loc][dd8 + p * 2 + j] * 1024.0f;
                f16 h = (f16)s;
                f16 l = (f16)(s - (float)h);
                hword |= (uint32_t)__builtin_bit_cast(uint16_t, h) << (16 * j);
                lword |= (uint32_t)__builtin_bit_cast(uint16_t, l) << (16 * j);
            }
            ehw[p] = hword; elw[p] = lword;
        }
        const int hc  = c * 2 + (dd8 >> 5);
        const int off = hc * 8192 + n_loc * 64 + (((dd8 & 31) * 2) ^ ((n_loc & 3) << 4));
        *(uint4*)(pbase + off)         = *(uint4*)ehw;
        *(uint4*)(pbase + 65536 + off) = *(uint4*)elw;
    }
}

// ---------------------------------------------------------------- init bests
__global__ void vq_init(unsigned long long* __restrict__ bests) {
    int i = blockIdx.x * 256 + threadIdx.x;
    if (i < N_ROWS) bests[i] = ~0ull;
}

// ---------------------------------------------------------------- main MFMA GEMM + argmin
// 256x256 tile, 512 threads, 8 waves (2x4), per-wave 128x64.
// 8 half-chunks (BK=32), double-buffered 64 KB each, counted vmcnt(8):
// next-chunk staging stays in flight under this chunk's ds_read+MFMA.
__global__ __launch_bounds__(512, 2) void vq_main(
    const char* __restrict__ Ap, const char* __restrict__ Bp,
    const float* __restrict__ An, const float* __restrict__ Bn,
    unsigned long long* __restrict__ bests)
{
    __shared__ __align__(16) char Lds[2][65536];  // 8 segs x 8 KB each

    const int tid  = threadIdx.x;
    const int wid  = tid >> 6, lane = tid & 63;
    const int wr   = wid >> 2, wc = wid & 3;          // 2 x 4 waves
    const int rb   = blockIdx.x & 127, jb = blockIdx.x >> 7;
    const int row0 = rb * 256, c0 = jb * 256;
    const int hi = lane >> 4, ln = lane & 15;
    const int sxo = (hi * 16) ^ ((ln & 3) << 4);      // within 64-B row
    const int brow = (wc & 1) * 64;

    const char* a0 = Ap + (size_t)(2 * rb) * 131072;
    const char* a1 = a0 + 131072;
    const char* b0 = Bp + (size_t)(2 * jb) * 131072;
    const char* b1 = b0 + 131072;
    const char* srcs[8] = { a0, a0 + 65536, a1, a1 + 65536,
                            b0, b0 + 65536, b1, b1 + 65536 };

    f32x4 acc[8][4] = {};

#define STAGE(hcv, bv)                                                    \
    _Pragma("unroll")                                                     \
    for (int s = 0; s < 8; ++s)                                           \
        gload16(srcs[s] + (hcv) * 8192 + tid * 16,                        \
                Lds[bv] + s * 8192 + tid * 16)

    STAGE(0, 0);

#pragma unroll
    for (int hc = 0; hc < 8; ++hc) {
        const int cur = hc & 1;
        if (hc < 7) {
            STAGE(hc + 1, cur ^ 1);
            asm volatile("s_waitcnt vmcnt(8)" ::: "memory");   // chunk hc landed
        } else {
            asm volatile("s_waitcnt vmcnt(0)" ::: "memory");
        }
        __builtin_amdgcn_s_barrier();
        __builtin_amdgcn_sched_barrier(0);

        const char* Lp  = Lds[cur];
        const char* aHp = Lp + (wr * 2) * 8192;
        const char* aLp = aHp + 8192;
        const char* bHp = Lp + 32768 + ((wc >> 1) * 2) * 8192;
        const char* bLp = bHp + 8192;

        f16x8 ah[8], al[8], bh[4], bl[4];
#pragma unroll
        for (int mi = 0; mi < 8; ++mi) {
            ah[mi] = *(const f16x8*)(aHp + (mi * 16 + ln) * 64 + sxo);
            al[mi] = *(const f16x8*)(aLp + (mi * 16 + ln) * 64 + sxo);
        }
#pragma unroll
        for (int ni = 0; ni < 4; ++ni) {
            const int r = brow + ni * 16 + ln;
            bh[ni] = *(const f16x8*)(bHp + r * 64 + sxo);
            bl[ni] = *(const f16x8*)(bLp + r * 64 + sxo);
        }
        __builtin_amdgcn_s_setprio(1);
#pragma unroll
        for (int mi = 0; mi < 8; ++mi)
#pragma unroll
            for (int ni = 0; ni < 4; ++ni)
                acc[mi][ni] = __builtin_amdgcn_mfma_f32_16x16x32_f16(
                    ah[mi], bh[ni], acc[mi][ni], 0, 0, 0);
#pragma unroll
        for (int mi = 0; mi < 8; ++mi)
#pragma unroll
            for (int ni = 0; ni < 4; ++ni)
                acc[mi][ni] = __builtin_amdgcn_mfma_f32_16x16x32_f16(
                    al[mi], bh[ni], acc[mi][ni], 0, 0, 0);
#pragma unroll
        for (int mi = 0; mi < 8; ++mi)
#pragma unroll
            for (int ni = 0; ni < 4; ++ni)
                acc[mi][ni] = __builtin_amdgcn_mfma_f32_16x16x32_f16(
                    ah[mi], bl[ni], acc[mi][ni], 0, 0, 0);
        __builtin_amdgcn_s_setprio(0);
        __builtin_amdgcn_s_barrier();     // everyone done reading Lds[cur]
    }
#undef STAGE

    // ---- epilogue: dist + fused argmin
    float bnv[4];
#pragma unroll
    for (int ni = 0; ni < 4; ++ni)
        bnv[ni] = Bn[c0 + wc * 64 + ni * 16 + ln];
    const int rbase = row0 + wr * 128 + hi * 4;

#pragma unroll
    for (int mi = 0; mi < 8; ++mi) {
#pragma unroll
        for (int r = 0; r < 4; ++r) {
            float an = An[rbase + mi * 16 + r];
            unsigned long long best = ~0ull;
#pragma unroll
            for (int ni = 0; ni < 4; ++ni) {
                float sim  = acc[mi][ni][r] * 0x1p-20f;   // exact descale
                float t    = an + bnv[ni];
                float dist = t - 2.0f * sim;
                unsigned code = (unsigned)(c0 + wc * 64 + ni * 16 + ln);
                unsigned long long p =
                    ((unsigned long long)__float_as_uint(dist) << 32) | code;
                best = p < best ? p : best;
            }
#pragma unroll
            for (int mm = 1; mm < 16; mm <<= 1) {
                unsigned long long o = __shfl_xor(best, mm);
                best = o < best ? o : best;
            }
            if (ln == 0) atomicMin(&bests[rbase + mi * 16 + r], best);
        }
    }
}

// ---------------------------------------------------------------- gather + loss partials
__global__ void vq_gather(const float* __restrict__ x, const float* __restrict__ et,
                          const unsigned long long* __restrict__ bests,
                          float* __restrict__ out, float* __restrict__ part) {
    __shared__ float wsum[4];
    int w    = threadIdx.x >> 6;
    int lane = threadIdx.x & 63;
    int row  = blockIdx.x * 4 + w;
    int k    = (int)(unsigned)(bests[row] & 0xffffffffull);
    float4 q  = *(const float4*)&et[(size_t)k * DIM + lane * 4];
    float4 xv = *(const float4*)&x[(size_t)row * DIM + lane * 4];
    *(float4*)&out[(size_t)row * DIM + lane * 4] = q;
    float d0 = q.x - xv.x, d1 = q.y - xv.y, d2 = q.z - xv.z, d3 = q.w - xv.w;
    float s = d0 * d0 + d1 * d1 + d2 * d2 + d3 * d3;
#pragma unroll
    for (int m = 1; m < 64; m <<= 1) s += __shfl_xor(s, m);
    if (lane == 0) wsum[w] = s;
    __syncthreads();
    if (threadIdx.x == 0) part[blockIdx.x] = wsum[0] + wsum[1] + wsum[2] + wsum[3];
}

// ---------------------------------------------------------------- finalize loss
__global__ void vq_finalize(const float* __restrict__ part, float* __restrict__ lossOut) {
    __shared__ float sm[256];
    float s = 0.0f;
    for (int i = threadIdx.x; i < 8192; i += 256) s += part[i];
    sm[threadIdx.x] = s;
    __syncthreads();
    for (int st = 128; st > 0; st >>= 1) {
        if (threadIdx.x < st) sm[threadIdx.x] += sm[threadIdx.x + st];
        __syncthreads();
    }
    if (threadIdx.x == 0)
        lossOut[0] = 1.25f * (sm[0] / 8388608.0f);
}

// ---------------------------------------------------------------- launch
extern "C" void kernel_launch(void* const* d_in, const int* in_sizes, int n_in,
                              void* d_out, int out_size, void* d_ws, size_t ws_size,
                              hipStream_t stream) {
    const float* x = (const float*)d_in[0];   // [32768, 256]
    const float* e = (const float*)d_in[1];   // [256, 4096]
    float* out = (float*)d_out;
    float* ws  = (float*)d_ws;

    float* et   = ws + WS_ET;
    float* bn   = ws + WS_BN;
    float* an   = ws + WS_AN;
    float* part = ws + WS_PART;
    unsigned long long* bests = (unsigned long long*)(ws + WS_BEST);
    char*  Bp   = (char*)(ws + WS_BP);
    char*  Ap   = (char*)(ws + WS_AP);

    vq_prep_a<<<256, 256, 0, stream>>>(x, Ap, an);
    vq_prep_b<<<128, 256, 0, stream>>>(e, Bp, et);
    vq_rownorm<<<KCODES / 4, 256, 0, stream>>>(et, bn, KCODES);
    vq_init<<<N_ROWS / 256, 256, 0, stream>>>(bests);
    vq_main<<<2048, 512, 0, stream>>>(Ap, Bp, an, bn, bests);
    vq_gather<<<N_ROWS / 4, 256, 0, stream>>>(x, et, bests, out, part);
    vq_finalize<<<1, 256, 0, stream>>>(part, out + (size_t)N_ROWS * DIM);
}

// Round 8
// 349.520 us; speedup vs baseline: 1.0749x; 1.0749x over previous
//
#include <hip/hip_runtime.h>
#include <math.h>

typedef _Float16 f16;
typedef f16 f16x8 __attribute__((ext_vector_type(8)));
typedef float f32x4 __attribute__((ext_vector_type(4)));

#define N_ROWS 32768
#define DIM    256
#define KCODES 4096

// ws layout (float units)
#define WS_ET    0                           // et [4096][256] f32        (4 MB)
#define WS_BN    (WS_ET + KCODES*DIM)        // code norms [4096]
#define WS_AN    (WS_BN + KCODES)            // row norms [32768]
#define WS_PART  (WS_AN + N_ROWS)            // loss partials [8192]
#define WS_BEST  (WS_PART + 8192)            // u64 bests [32768] = 65536 floats
#define WS_BP    (WS_BEST + 65536)           // B' images  4 MB = 1048576 floats
#define WS_AP    (WS_BP + 1048576)           // A' images 32 MB = 8388608 floats

// Image geometry (R6, proven 0-conflict): chunk = [128 rows][64 f16 = 128 B],
// swizzled byte_in_row = (dd*2) ^ ((row & 7) << 4).
// Per-128-row A' block: 131072 B (H plane: 4 chunks x 16384 @0; L @65536)
// Per-128-code B' block: 131072 B (EH @0; EL @65536)
// Virtual K=768 GEMM, 12 K-tiles (BK=64):
//   t 0-3: A=H(t),  B=EH(t) | t 4-7: A=L(t-4), B=EH(t-4) | t 8-11: A=H, B=EL
// -> accumulation chain per element identical to R4/R5 (absmax 2.441e-4).

// ---------------------------------------------------------------- helpers
__device__ __forceinline__ void gload16(const void* g, void* l) {
#if __has_builtin(__builtin_amdgcn_global_load_lds)
    __builtin_amdgcn_global_load_lds(
        (const __attribute__((address_space(1))) unsigned int*)g,
        (__attribute__((address_space(3))) unsigned int*)l, 16, 0, 0);
#else
    *(float4*)l = *(const float4*)g;
#endif
}

__device__ __forceinline__ constexpr int aoff_of(int t) {
    return (t & 3) * 16384 + (((t >> 2) == 1) ? 65536 : 0);
}
__device__ __forceinline__ constexpr int boff_of(int t) {
    return (t & 3) * 16384 + (((t >> 2) == 2) ? 65536 : 0);
}

// ---------------------------------------------------------------- row norms (codes)
__global__ void vq_rownorm(const float* __restrict__ src, float* __restrict__ out, int nrows) {
    int w    = threadIdx.x >> 6;
    int lane = threadIdx.x & 63;
    int row  = blockIdx.x * 4 + w;
    if (row >= nrows) return;
    float4 v = *(const float4*)&src[row * DIM + lane * 4];
    float  s = v.x * v.x + v.y * v.y + v.z * v.z + v.w * v.w;
#pragma unroll
    for (int m = 1; m < 64; m <<= 1) s += __shfl_xor(s, m);
    if (lane == 0) out[row] = s;
}

// ---------------------------------------------------------------- A' prep (+ fused x row norms)  [R6 verbatim]
__global__ void vq_prep_a(const float* __restrict__ x, char* __restrict__ Ap,
                          float* __restrict__ An) {
    const int t = threadIdx.x;
    const int lane = t & 63, w = t >> 6;
    const size_t row0 = (size_t)blockIdx.x * 128;
    char* base = Ap + (size_t)blockIdx.x * 131072;
    const int chunk = lane >> 4;
    const int dd2   = (lane & 15) * 8;
#pragma unroll 4
    for (int it = 0; it < 32; ++it) {
        const int m = it * 4 + w;
        float4 v = *(const float4*)&x[(row0 + m) * DIM + lane * 4];
        float vs[4] = { v.x, v.y, v.z, v.w };
        uint32_t hw[2], lw[2];
#pragma unroll
        for (int p = 0; p < 2; ++p) {
            uint32_t hword = 0, lword = 0;
#pragma unroll
            for (int j = 0; j < 2; ++j) {
                float s = vs[p * 2 + j] * 1024.0f;
                f16 h = (f16)s;
                f16 l = (f16)(s - (float)h);
                hword |= (uint32_t)__builtin_bit_cast(uint16_t, h) << (16 * j);
                lword |= (uint32_t)__builtin_bit_cast(uint16_t, l) << (16 * j);
            }
            hw[p] = hword; lw[p] = lword;
        }
        const int off = chunk * 16384 + m * 128 + (dd2 ^ ((m & 7) << 4));
        *(uint2*)(base + off)         = *(uint2*)hw;
        *(uint2*)(base + 65536 + off) = *(uint2*)lw;
        float s = v.x * v.x + v.y * v.y + v.z * v.z + v.w * v.w;
#pragma unroll
        for (int mm = 1; mm < 64; mm <<= 1) s += __shfl_xor(s, mm);
        if (lane == 0) An[row0 + m] = s;
    }
}

// ---------------------------------------------------------------- B' prep (+ writes et)  [R6 verbatim]
__global__ void vq_prep_b(const float* __restrict__ e, char* __restrict__ Bp,
                          float* __restrict__ et) {
    __shared__ float lt[128][65];
    const int t  = threadIdx.x;
    const int jb = blockIdx.x >> 2;
    const int c  = blockIdx.x & 3;
    const int d0 = c * 64, n0 = jb * 128;
#pragma unroll
    for (int it = 0; it < 8; ++it) {
        int linear = it * 256 + t;
        int drow = linear >> 5;
        int ncol = (linear & 31) * 4;
        float4 v = *(const float4*)&e[(size_t)(d0 + drow) * KCODES + n0 + ncol];
        lt[ncol + 0][drow] = v.x;
        lt[ncol + 1][drow] = v.y;
        lt[ncol + 2][drow] = v.z;
        lt[ncol + 3][drow] = v.w;
    }
    __syncthreads();
#pragma unroll
    for (int it = 0; it < 8; ++it) {
        int lin = it * 256 + t;
        int n = lin >> 4, q = lin & 15;
        float4 v = { lt[n][q*4], lt[n][q*4+1], lt[n][q*4+2], lt[n][q*4+3] };
        *(float4*)&et[(size_t)(n0 + n) * DIM + d0 + q * 4] = v;
    }
    char* ehbase = Bp + (size_t)jb * 131072 + c * 16384;
    const int n_loc = t >> 1;
    const int shalf = t & 1;
#pragma unroll
    for (int g = 0; g < 4; ++g) {
        const int dd8 = shalf * 32 + g * 8;
        uint32_t ehw[4], elw[4];
#pragma unroll
        for (int p = 0; p < 4; ++p) {
            uint32_t hword = 0, lword = 0;
#pragma unroll
            for (int j = 0; j < 2; ++j) {
                float s = lt[n_loc][dd8 + p * 2 + j] * 1024.0f;
                f16 h = (f16)s;
                f16 l = (f16)(s - (float)h);
                hword |= (uint32_t)__builtin_bit_cast(uint16_t, h) << (16 * j);
                lword |= (uint32_t)__builtin_bit_cast(uint16_t, l) << (16 * j);
            }
            ehw[p] = hword; elw[p] = lword;
        }
        const int off = n_loc * 128 + ((dd8 * 2) ^ ((n_loc & 7) << 4));
        *(uint4*)(ehbase + off)         = *(uint4*)ehw;
        *(uint4*)(ehbase + 65536 + off) = *(uint4*)elw;
    }
}

// ---------------------------------------------------------------- init bests
__global__ void vq_init(unsigned long long* __restrict__ bests) {
    int i = blockIdx.x * 256 + threadIdx.x;
    if (i < N_ROWS) bests[i] = ~0ull;
}

// ---------------------------------------------------------------- main MFMA GEMM + argmin
// 256x256 tile, 8 waves (2x4), virtual K=768 as 12 BK=64 tiles.
// Per tile: 4 phases {ds_read || stage 1 half of tile t+1 -> barrier ->
// lgkmcnt(0) -> 16 MFMA -> barrier}; vmcnt(2) at tile boundary only.
// LDS: 2 slots x 64 KB (tile t in slot t&1; t+1 stages into ~(t&1)).
__global__ __launch_bounds__(512, 2) void vq_main(
    const char* __restrict__ Ap, const char* __restrict__ Bp,
    const float* __restrict__ An, const float* __restrict__ Bn,
    unsigned long long* __restrict__ bests)
{
    __shared__ __align__(16) char Lds[2][65536];

    const int tid  = threadIdx.x;
    const int wid  = tid >> 6, lane = tid & 63;
    const int wr   = wid >> 2, wc = wid & 3;          // 2 x 4 waves
    const int rb   = blockIdx.x & 127, jb = blockIdx.x >> 7;
    const int row0 = rb * 256, c0 = jb * 256;
    const int hi = lane >> 4, ln = lane & 15;
    const int sx = (lane & 7) << 4;

    const char* a0 = Ap + (size_t)(2 * rb) * 131072;   // rows 0-127
    const char* a1 = a0 + 131072;                      // rows 128-255
    const char* b0 = Bp + (size_t)(2 * jb) * 131072;   // codes 0-127
    const char* b1 = b0 + 131072;                      // codes 128-255

    f32x4 acc[8][4] = {};
    f16x8 bf[4];

    // half j of tile tt: j=0,1 -> A row-halves; j=2,3 -> B code-halves
#define STAGE_HALF(j, tt)                                                    \
    do {                                                                     \
        const char* _s = (j) == 0 ? a0 + aoff_of(tt)                         \
                       : (j) == 1 ? a1 + aoff_of(tt)                         \
                       : (j) == 2 ? b0 + boff_of(tt)                         \
                                  : b1 + boff_of(tt);                        \
        char* _d = (char*)Lds[(tt) & 1] + (j) * 16384;                       \
        gload16(_s + tid * 16,        _d + tid * 16);                        \
        gload16(_s + 8192 + tid * 16, _d + 8192 + tid * 16);                 \
    } while (0)

    // prologue: stage tile 0 into slot 0 (8 instrs in flight)
#pragma unroll
    for (int j = 0; j < 4; ++j) STAGE_HALF(j, 0);

#pragma unroll
    for (int t = 0; t < 12; ++t) {
        const char* slot = Lds[t & 1];
        const char* aH = slot + wr * 16384;                   // this wave's A half
        const char* bB = slot + 32768 + (wc >> 1) * 16384;    // this wave's B half

#pragma unroll
        for (int q = 0; q < 4; ++q) {
            const int ks = q >> 1, mh = q & 1;
            const int ko = (ks * 64 + hi * 16) ^ sx;
            f16x8 af[4];

            if (q == 0) {
                // boundary: ensure tile t landed; keep new loads in flight
                if (t < 11) {
                    STAGE_HALF(0, t + 1);
                    asm volatile("s_waitcnt vmcnt(2)" ::: "memory");
                } else {
                    asm volatile("s_waitcnt vmcnt(0)" ::: "memory");
                }
                __builtin_amdgcn_s_barrier();
                __builtin_amdgcn_sched_barrier(0);
#pragma unroll
                for (int ni = 0; ni < 4; ++ni)
                    bf[ni] = *(const f16x8*)(bB + ((wc & 1) * 64 + ni * 16 + ln) * 128 + ko);
#pragma unroll
                for (int i = 0; i < 4; ++i)
                    af[i] = *(const f16x8*)(aH + ((mh * 4 + i) * 16 + ln) * 128 + ko);
            } else {
                if (q == 2) {
#pragma unroll
                    for (int ni = 0; ni < 4; ++ni)
                        bf[ni] = *(const f16x8*)(bB + ((wc & 1) * 64 + ni * 16 + ln) * 128 + ko);
                }
#pragma unroll
                for (int i = 0; i < 4; ++i)
                    af[i] = *(const f16x8*)(aH + ((mh * 4 + i) * 16 + ln) * 128 + ko);
                if (t < 11) STAGE_HALF(q, t + 1);
                __builtin_amdgcn_s_barrier();
            }

            asm volatile("s_waitcnt lgkmcnt(0)" ::: "memory");
            __builtin_amdgcn_sched_barrier(0);
            __builtin_amdgcn_s_setprio(1);
#pragma unroll
            for (int i = 0; i < 4; ++i)
#pragma unroll
                for (int ni = 0; ni < 4; ++ni)
                    acc[mh * 4 + i][ni] = __builtin_amdgcn_mfma_f32_16x16x32_f16(
                        af[i], bf[ni], acc[mh * 4 + i][ni], 0, 0, 0);
            __builtin_amdgcn_s_setprio(0);
            __builtin_amdgcn_s_barrier();
        }
    }
#undef STAGE_HALF

    // ---- epilogue: dist + fused argmin
    float bnv[4];
#pragma unroll
    for (int ni = 0; ni < 4; ++ni)
        bnv[ni] = Bn[c0 + wc * 64 + ni * 16 + ln];
    const int rbase = row0 + wr * 128 + hi * 4;

#pragma unroll
    for (int mi = 0; mi < 8; ++mi) {
#pragma unroll
        for (int r = 0; r < 4; ++r) {
            float an = An[rbase + mi * 16 + r];
            unsigned long long best = ~0ull;
#pragma unroll
            for (int ni = 0; ni < 4; ++ni) {
                float sim  = acc[mi][ni][r] * 0x1p-20f;   // exact descale
                float t    = an + bnv[ni];
                float dist = t - 2.0f * sim;
                unsigned code = (unsigned)(c0 + wc * 64 + ni * 16 + ln);
                unsigned long long p =
                    ((unsigned long long)__float_as_uint(dist) << 32) | code;
                best = p < best ? p : best;
            }
#pragma unroll
            for (int mm = 1; mm < 16; mm <<= 1) {
                unsigned long long o = __shfl_xor(best, mm);
                best = o < best ? o : best;
            }
            if (ln == 0) atomicMin(&bests[rbase + mi * 16 + r], best);
        }
    }
}

// ---------------------------------------------------------------- gather + loss partials
__global__ void vq_gather(const float* __restrict__ x, const float* __restrict__ et,
                          const unsigned long long* __restrict__ bests,
                          float* __restrict__ out, float* __restrict__ part) {
    __shared__ float wsum[4];
    int w    = threadIdx.x >> 6;
    int lane = threadIdx.x & 63;
    int row  = blockIdx.x * 4 + w;
    int k    = (int)(unsigned)(bests[row] & 0xffffffffull);
    float4 q  = *(const float4*)&et[(size_t)k * DIM + lane * 4];
    float4 xv = *(const float4*)&x[(size_t)row * DIM + lane * 4];
    *(float4*)&out[(size_t)row * DIM + lane * 4] = q;
    float d0 = q.x - xv.x, d1 = q.y - xv.y, d2 = q.z - xv.z, d3 = q.w - xv.w;
    float s = d0 * d0 + d1 * d1 + d2 * d2 + d3 * d3;
#pragma unroll
    for (int m = 1; m < 64; m <<= 1) s += __shfl_xor(s, m);
    if (lane == 0) wsum[w] = s;
    __syncthreads();
    if (threadIdx.x == 0) part[blockIdx.x] = wsum[0] + wsum[1] + wsum[2] + wsum[3];
}

// ---------------------------------------------------------------- finalize loss
__global__ void vq_finalize(const float* __restrict__ part, float* __restrict__ lossOut) {
    __shared__ float sm[256];
    float s = 0.0f;
    for (int i = threadIdx.x; i < 8192; i += 256) s += part[i];
    sm[threadIdx.x] = s;
    __syncthreads();
    for (int st = 128; st > 0; st >>= 1) {
        if (threadIdx.x < st) sm[threadIdx.x] += sm[threadIdx.x + st];
        __syncthreads();
    }
    if (threadIdx.x == 0)
        lossOut[0] = 1.25f * (sm[0] / 8388608.0f);
}

// ---------------------------------------------------------------- launch
extern "C" void kernel_launch(void* const* d_in, const int* in_sizes, int n_in,
                              void* d_out, int out_size, void* d_ws, size_t ws_size,
                              hipStream_t stream) {
    const float* x = (const float*)d_in[0];   // [32768, 256]
    const float* e = (const float*)d_in[1];   // [256, 4096]
    float* out = (float*)d_out;
    float* ws  = (float*)d_ws;

    float* et   = ws + WS_ET;
    float* bn   = ws + WS_BN;
    float* an   = ws + WS_AN;
    float* part = ws + WS_PART;
    unsigned long long* bests = (unsigned long long*)(ws + WS_BEST);
    char*  Bp   = (char*)(ws + WS_BP);
    char*  Ap   = (char*)(ws + WS_AP);

    vq_prep_a<<<256, 256, 0, stream>>>(x, Ap, an);
    vq_prep_b<<<128, 256, 0, stream>>>(e, Bp, et);
    vq_rownorm<<<KCODES / 4, 256, 0, stream>>>(et, bn, KCODES);
    vq_init<<<N_ROWS / 256, 256, 0, stream>>>(bests);
    vq_main<<<2048, 512, 0, stream>>>(Ap, Bp, an, bn, bests);
    vq_gather<<<N_ROWS / 4, 256, 0, stream>>>(x, et, bests, out, part);
    vq_finalize<<<1, 256, 0, stream>>>(part, out + (size_t)N_ROWS * DIM);
}

// Round 9
// 284.831 us; speedup vs baseline: 1.3190x; 1.2271x over previous
//
#include <hip/hip_runtime.h>
#include <math.h>

typedef _Float16 f16;
typedef f16 f16x8 __attribute__((ext_vector_type(8)));
typedef float f32x4 __attribute__((ext_vector_type(4)));

#define N_ROWS 32768
#define DIM    256
#define KCODES 4096

// ws layout (float units)
#define WS_ET    0                           // et [4096][256] f32        (4 MB)
#define WS_BN    (WS_ET + KCODES*DIM)        // code norms [4096]
#define WS_AN    (WS_BN + KCODES)            // row norms [32768]
#define WS_PART  (WS_AN + N_ROWS)            // loss partials [8192]
#define WS_IDX   (WS_PART + 8192)            // argmin idx [32768] (int)
#define WS_BP    (WS_IDX + N_ROWS)           // B' images  4 MB = 1048576 floats
#define WS_AP    (WS_BP + 1048576)           // A' images 32 MB = 8388608 floats

// Image geometry (R6, proven 0-conflict): chunk = [128 rows][64 f16 = 128 B],
// swizzled byte_in_row = (dd*2) ^ ((row & 7) << 4).
// Per-128-row A' block: 131072 B (H plane: 4 chunks x 16384 @0; L @65536)
// Per-128-code B' block: 131072 B (EH @0; EL @65536)
// sim*2^20 = H.EH + L.EH + H.EL (l*l dropped, ~4e-7 in dist units)

// ---------------------------------------------------------------- helpers
__device__ __forceinline__ void gload16(const void* g, void* l) {
#if __has_builtin(__builtin_amdgcn_global_load_lds)
    __builtin_amdgcn_global_load_lds(
        (const __attribute__((address_space(1))) unsigned int*)g,
        (__attribute__((address_space(3))) unsigned int*)l, 16, 0, 0);
#else
    *(float4*)l = *(const float4*)g;
#endif
}

// ---------------------------------------------------------------- row norms (codes)
__global__ void vq_rownorm(const float* __restrict__ src, float* __restrict__ out, int nrows) {
    int w    = threadIdx.x >> 6;
    int lane = threadIdx.x & 63;
    int row  = blockIdx.x * 4 + w;
    if (row >= nrows) return;
    float4 v = *(const float4*)&src[row * DIM + lane * 4];
    float  s = v.x * v.x + v.y * v.y + v.z * v.z + v.w * v.w;
#pragma unroll
    for (int m = 1; m < 64; m <<= 1) s += __shfl_xor(s, m);
    if (lane == 0) out[row] = s;
}

// ---------------------------------------------------------------- A' prep (+ fused x row norms)
__global__ void vq_prep_a(const float* __restrict__ x, char* __restrict__ Ap,
                          float* __restrict__ An) {
    const int t = threadIdx.x;
    const int lane = t & 63, w = t >> 6;
    const size_t row0 = (size_t)blockIdx.x * 128;
    char* base = Ap + (size_t)blockIdx.x * 131072;
    const int chunk = lane >> 4;
    const int dd2   = (lane & 15) * 8;
#pragma unroll 4
    for (int it = 0; it < 32; ++it) {
        const int m = it * 4 + w;
        float4 v = *(const float4*)&x[(row0 + m) * DIM + lane * 4];
        float vs[4] = { v.x, v.y, v.z, v.w };
        uint32_t hw[2], lw[2];
#pragma unroll
        for (int p = 0; p < 2; ++p) {
            uint32_t hword = 0, lword = 0;
#pragma unroll
            for (int j = 0; j < 2; ++j) {
                float s = vs[p * 2 + j] * 1024.0f;
                f16 h = (f16)s;
                f16 l = (f16)(s - (float)h);
                hword |= (uint32_t)__builtin_bit_cast(uint16_t, h) << (16 * j);
                lword |= (uint32_t)__builtin_bit_cast(uint16_t, l) << (16 * j);
            }
            hw[p] = hword; lw[p] = lword;
        }
        const int off = chunk * 16384 + m * 128 + (dd2 ^ ((m & 7) << 4));
        *(uint2*)(base + off)         = *(uint2*)hw;
        *(uint2*)(base + 65536 + off) = *(uint2*)lw;
        float s = v.x * v.x + v.y * v.y + v.z * v.z + v.w * v.w;
#pragma unroll
        for (int mm = 1; mm < 64; mm <<= 1) s += __shfl_xor(s, mm);
        if (lane == 0) An[row0 + m] = s;
    }
}

// ---------------------------------------------------------------- B' prep (+ writes et)
__global__ void vq_prep_b(const float* __restrict__ e, char* __restrict__ Bp,
                          float* __restrict__ et) {
    __shared__ float lt[128][65];
    const int t  = threadIdx.x;
    const int jb = blockIdx.x >> 2;
    const int c  = blockIdx.x & 3;
    const int d0 = c * 64, n0 = jb * 128;
#pragma unroll
    for (int it = 0; it < 8; ++it) {
        int linear = it * 256 + t;
        int drow = linear >> 5;
        int ncol = (linear & 31) * 4;
        float4 v = *(const float4*)&e[(size_t)(d0 + drow) * KCODES + n0 + ncol];
        lt[ncol + 0][drow] = v.x;
        lt[ncol + 1][drow] = v.y;
        lt[ncol + 2][drow] = v.z;
        lt[ncol + 3][drow] = v.w;
    }
    __syncthreads();
#pragma unroll
    for (int it = 0; it < 8; ++it) {
        int lin = it * 256 + t;
        int n = lin >> 4, q = lin & 15;
        float4 v = { lt[n][q*4], lt[n][q*4+1], lt[n][q*4+2], lt[n][q*4+3] };
        *(float4*)&et[(size_t)(n0 + n) * DIM + d0 + q * 4] = v;
    }
    char* ehbase = Bp + (size_t)jb * 131072 + c * 16384;
    const int n_loc = t >> 1;
    const int shalf = t & 1;
#pragma unroll
    for (int g = 0; g < 4; ++g) {
        const int dd8 = shalf * 32 + g * 8;
        uint32_t ehw[4], elw[4];
#pragma unroll
        for (int p = 0; p < 4; ++p) {
            uint32_t hword = 0, lword = 0;
#pragma unroll
            for (int j = 0; j < 2; ++j) {
                float s = lt[n_loc][dd8 + p * 2 + j] * 1024.0f;
                f16 h = (f16)s;
                f16 l = (f16)(s - (float)h);
                hword |= (uint32_t)__builtin_bit_cast(uint16_t, h) << (16 * j);
                lword |= (uint32_t)__builtin_bit_cast(uint16_t, l) << (16 * j);
            }
            ehw[p] = hword; elw[p] = lword;
        }
        const int off = n_loc * 128 + ((dd8 * 2) ^ ((n_loc & 7) << 4));
        *(uint4*)(ehbase + off)         = *(uint4*)ehw;
        *(uint4*)(ehbase + 65536 + off) = *(uint4*)elw;
    }
}

// ---------------------------------------------------------------- main MFMA GEMM + argmin
// Grid 256 (1 block/CU), 512 thr, 8 waves (2 wr x 4 wc), block owns 128 rows.
// Loops 16 iters x 256 codes; per iter 4 chunks (BK=64) as X/Y phases:
//   X: aH.(bEH,bEL)  64 MFMA | Y: aL.bEH (bEH regs)  32 MFMA
// LDS: aH dbuf 2x16K + aL 16K + bEH 32K + bEL 32K + red 4K = 116 KB.
// Counted vmcnt pipeline: X issues aL(t) -> vmcnt(2); Y issues {aH,bEH,bEL}(t+1)
// -> vmcnt(10). Extra older loads (an/bn) only strengthen waits (safe).
__global__ __launch_bounds__(512, 2) void vq_main(
    const char* __restrict__ Ap, const char* __restrict__ Bp,
    const float* __restrict__ An, const float* __restrict__ Bn,
    int* __restrict__ idxOut)
{
    __shared__ __align__(16) char LaH[2][16384];
    __shared__ __align__(16) char LaL[16384];
    __shared__ __align__(16) char LbEH[32768];
    __shared__ __align__(16) char LbEL[32768];
    __shared__ unsigned long long red[128][4];

    const int tid = threadIdx.x;
    const int wid = tid >> 6, lane = tid & 63;
    const int wr = wid >> 2, wc = wid & 3;            // 2 x 4 waves
    const int hi = lane >> 4, ln = lane & 15;
    const int sx = (lane & 7) << 4;
    const size_t row0 = (size_t)blockIdx.x * 128;
    const char* abase = Ap + (size_t)blockIdx.x * 131072;

    // per-lane row norms (held)
    float an[16];
#pragma unroll
    for (int mi = 0; mi < 4; ++mi)
#pragma unroll
        for (int r = 0; r < 4; ++r)
            an[mi * 4 + r] = An[row0 + wr * 64 + mi * 16 + hi * 4 + r];

    unsigned long long run[16];
#pragma unroll
    for (int v = 0; v < 16; ++v) run[v] = ~0ull;

    // stage for step t+1: aH -> slot (t+1)&1, bEH, bEL (10 loads)
#define ISSUE_Y(t)                                                           \
    do {                                                                     \
        const int tn = ((t) + 1) & 63;                                       \
        const int c_ = tn & 3, it_ = tn >> 2;                                \
        const char* b0_ = Bp + (size_t)(2 * it_) * 131072;                   \
        const char* b1_ = b0_ + 131072;                                      \
        char* ah_ = (char*)LaH[tn & 1];                                      \
        gload16(abase + c_ * 16384 + tid * 16,        ah_ + tid * 16);       \
        gload16(abase + c_ * 16384 + 8192 + tid * 16, ah_ + 8192 + tid * 16);\
        gload16(b0_ + c_ * 16384 + tid * 16,        LbEH + tid * 16);        \
        gload16(b0_ + c_ * 16384 + 8192 + tid * 16, LbEH + 8192 + tid * 16); \
        gload16(b1_ + c_ * 16384 + tid * 16,        LbEH + 16384 + tid * 16);\
        gload16(b1_ + c_ * 16384 + 8192 + tid * 16, LbEH + 24576 + tid * 16);\
        gload16(b0_ + 65536 + c_ * 16384 + tid * 16,        LbEL + tid * 16);\
        gload16(b0_ + 65536 + c_ * 16384 + 8192 + tid * 16, LbEL + 8192 + tid * 16);\
        gload16(b1_ + 65536 + c_ * 16384 + tid * 16,        LbEL + 16384 + tid * 16);\
        gload16(b1_ + 65536 + c_ * 16384 + 8192 + tid * 16, LbEL + 24576 + tid * 16);\
    } while (0)

#define ISSUE_X(t)                                                           \
    do {                                                                     \
        const int c_ = (t) & 3;                                              \
        gload16(abase + 65536 + c_ * 16384 + tid * 16,        LaL + tid * 16);\
        gload16(abase + 65536 + c_ * 16384 + 8192 + tid * 16, LaL + 8192 + tid * 16);\
    } while (0)

    f32x4 acc[4][4] = {};

    ISSUE_Y(63);   // stages t=0

#pragma unroll 1
    for (int t = 0; t < 64; ++t) {
        // ---------------- phase X ----------------
        ISSUE_X(t);
        asm volatile("s_waitcnt vmcnt(2)" ::: "memory");   // aH,bEH,bEL(t) landed
        __builtin_amdgcn_s_barrier();
        __builtin_amdgcn_sched_barrier(0);

        const char* ah = LaH[t & 1];
        f16x8 aH[8], bH[8], bL[8];
#pragma unroll
        for (int ks = 0; ks < 2; ++ks) {
            const int ko = (ks * 64 + hi * 16) ^ sx;
#pragma unroll
            for (int i = 0; i < 4; ++i)
                aH[ks * 4 + i] = *(const f16x8*)(ah + (wr * 64 + i * 16 + ln) * 128 + ko);
#pragma unroll
            for (int ni = 0; ni < 4; ++ni) {
                const int brow = ((wc & 1) * 64 + ni * 16 + ln) * 128 + ko;
                bH[ks * 4 + ni] = *(const f16x8*)(LbEH + (wc >> 1) * 16384 + brow);
                bL[ks * 4 + ni] = *(const f16x8*)(LbEL + (wc >> 1) * 16384 + brow);
            }
        }
        __builtin_amdgcn_s_setprio(1);
#pragma unroll
        for (int ks = 0; ks < 2; ++ks)
#pragma unroll
            for (int mi = 0; mi < 4; ++mi)
#pragma unroll
                for (int ni = 0; ni < 4; ++ni)
                    acc[mi][ni] = __builtin_amdgcn_mfma_f32_16x16x32_f16(
                        aH[ks * 4 + mi], bH[ks * 4 + ni], acc[mi][ni], 0, 0, 0);
#pragma unroll
        for (int ks = 0; ks < 2; ++ks)
#pragma unroll
            for (int mi = 0; mi < 4; ++mi)
#pragma unroll
                for (int ni = 0; ni < 4; ++ni)
                    acc[mi][ni] = __builtin_amdgcn_mfma_f32_16x16x32_f16(
                        aH[ks * 4 + mi], bL[ks * 4 + ni], acc[mi][ni], 0, 0, 0);
        __builtin_amdgcn_s_setprio(0);
        __builtin_amdgcn_s_barrier();      // close X: all waves done with LDS reads

        // ---------------- phase Y ----------------
        ISSUE_Y(t);
        asm volatile("s_waitcnt vmcnt(10)" ::: "memory");  // aL(t) landed
        __builtin_amdgcn_s_barrier();
        __builtin_amdgcn_sched_barrier(0);

        f16x8 aL[8];
#pragma unroll
        for (int ks = 0; ks < 2; ++ks) {
            const int ko = (ks * 64 + hi * 16) ^ sx;
#pragma unroll
            for (int i = 0; i < 4; ++i)
                aL[ks * 4 + i] = *(const f16x8*)(LaL + (wr * 64 + i * 16 + ln) * 128 + ko);
        }
        __builtin_amdgcn_s_setprio(1);
#pragma unroll
        for (int ks = 0; ks < 2; ++ks)
#pragma unroll
            for (int mi = 0; mi < 4; ++mi)
#pragma unroll
                for (int ni = 0; ni < 4; ++ni)
                    acc[mi][ni] = __builtin_amdgcn_mfma_f32_16x16x32_f16(
                        aL[ks * 4 + mi], bH[ks * 4 + ni], acc[mi][ni], 0, 0, 0);
        __builtin_amdgcn_s_setprio(0);
        __builtin_amdgcn_s_barrier();      // close Y

        // ---------------- per-iter argmin epilogue ----------------
        if ((t & 3) == 3) {
            const int it = t >> 2;
            float bn[4];
#pragma unroll
            for (int ni = 0; ni < 4; ++ni)
                bn[ni] = Bn[it * 256 + wc * 64 + ni * 16 + ln];
#pragma unroll
            for (int mi = 0; mi < 4; ++mi)
#pragma unroll
                for (int r = 0; r < 4; ++r) {
                    const float a = an[mi * 4 + r];
                    unsigned long long best = run[mi * 4 + r];
#pragma unroll
                    for (int ni = 0; ni < 4; ++ni) {
                        float sim  = acc[mi][ni][r] * 0x1p-20f;
                        float tt   = a + bn[ni];
                        float dist = tt - 2.0f * sim;
                        unsigned code = (unsigned)(it * 256 + wc * 64 + ni * 16 + ln);
                        unsigned long long p =
                            ((unsigned long long)__float_as_uint(dist) << 32) | code;
                        best = p < best ? p : best;
                    }
                    run[mi * 4 + r] = best;
                }
#pragma unroll
            for (int mi = 0; mi < 4; ++mi)
#pragma unroll
                for (int ni = 0; ni < 4; ++ni)
                    acc[mi][ni] = f32x4{0.f, 0.f, 0.f, 0.f};
        }
    }
#undef ISSUE_X
#undef ISSUE_Y

    // ---- final reduce: over ln (codes within wave), then over wc via LDS
#pragma unroll
    for (int v = 0; v < 16; ++v) {
#pragma unroll
        for (int m = 1; m < 16; m <<= 1) {
            unsigned long long o = __shfl_xor(run[v], m);
            run[v] = o < run[v] ? o : run[v];
        }
    }
    if (ln == 0) {
#pragma unroll
        for (int mi = 0; mi < 4; ++mi)
#pragma unroll
            for (int r = 0; r < 4; ++r)
                red[wr * 64 + mi * 16 + hi * 4 + r][wc] = run[mi * 4 + r];
    }
    __syncthreads();
    if (tid < 128) {
        unsigned long long b = red[tid][0];
#pragma unroll
        for (int w = 1; w < 4; ++w) {
            unsigned long long o = red[tid][w];
            b = o < b ? o : b;
        }
        idxOut[row0 + tid] = (int)(unsigned)(b & 0xffffffffull);
    }
}

// ---------------------------------------------------------------- gather + loss partials
__global__ void vq_gather(const float* __restrict__ x, const float* __restrict__ et,
                          const int* __restrict__ idx,
                          float* __restrict__ out, float* __restrict__ part) {
    __shared__ float wsum[4];
    int w    = threadIdx.x >> 6;
    int lane = threadIdx.x & 63;
    int row  = blockIdx.x * 4 + w;
    int k    = idx[row];
    float4 q  = *(const float4*)&et[(size_t)k * DIM + lane * 4];
    float4 xv = *(const float4*)&x[(size_t)row * DIM + lane * 4];
    *(float4*)&out[(size_t)row * DIM + lane * 4] = q;
    float d0 = q.x - xv.x, d1 = q.y - xv.y, d2 = q.z - xv.z, d3 = q.w - xv.w;
    float s = d0 * d0 + d1 * d1 + d2 * d2 + d3 * d3;
#pragma unroll
    for (int m = 1; m < 64; m <<= 1) s += __shfl_xor(s, m);
    if (lane == 0) wsum[w] = s;
    __syncthreads();
    if (threadIdx.x == 0) part[blockIdx.x] = wsum[0] + wsum[1] + wsum[2] + wsum[3];
}

// ---------------------------------------------------------------- finalize loss
__global__ void vq_finalize(const float* __restrict__ part, float* __restrict__ lossOut) {
    __shared__ float sm[256];
    float s = 0.0f;
    for (int i = threadIdx.x; i < 8192; i += 256) s += part[i];
    sm[threadIdx.x] = s;
    __syncthreads();
    for (int st = 128; st > 0; st >>= 1) {
        if (threadIdx.x < st) sm[threadIdx.x] += sm[threadIdx.x + st];
        __syncthreads();
    }
    if (threadIdx.x == 0)
        lossOut[0] = 1.25f * (sm[0] / 8388608.0f);
}

// ---------------------------------------------------------------- launch
extern "C" void kernel_launch(void* const* d_in, const int* in_sizes, int n_in,
                              void* d_out, int out_size, void* d_ws, size_t ws_size,
                              hipStream_t stream) {
    const float* x = (const float*)d_in[0];   // [32768, 256]
    const float* e = (const float*)d_in[1];   // [256, 4096]
    float* out = (float*)d_out;
    float* ws  = (float*)d_ws;

    float* et   = ws + WS_ET;
    float* bn   = ws + WS_BN;
    float* an   = ws + WS_AN;
    float* part = ws + WS_PART;
    int*   idx  = (int*)(ws + WS_IDX);
    char*  Bp   = (char*)(ws + WS_BP);
    char*  Ap   = (char*)(ws + WS_AP);

    vq_prep_a<<<256, 256, 0, stream>>>(x, Ap, an);
    vq_prep_b<<<128, 256, 0, stream>>>(e, Bp, et);
    vq_rownorm<<<KCODES / 4, 256, 0, stream>>>(et, bn, KCODES);
    vq_main<<<256, 512, 0, stream>>>(Ap, Bp, an, bn, idx);
    vq_gather<<<N_ROWS / 4, 256, 0, stream>>>(x, et, idx, out, part);
    vq_finalize<<<1, 256, 0, stream>>>(part, out + (size_t)N_ROWS * DIM);
}